// Round 22
// baseline (294.876 us; speedup 1.0000x reference)
//
#include <hip/hip_runtime.h>
#include <hip/hip_fp16.h>

#define IMG_H 1024
#define IMG_W 1024
#define NIMG  16
#define RAD   5
#define KW    11
#define TX    32              // block tile width (cols); 16 per wave, 2 waves
#define WTX   16              // cols per wave
#define STRIP 128             // tile height (rows per block)
#define ASTEP 16              // h-blur rows per A step
#define BSTEP 16              // output rows per B step
#define HBROWS (STRIP + 2*RAD)   // 138 h-blurred rows per strip
#define RING  32              // ring rows per wave (pow2: slot = h & 31)
#define WPAD  20              // halfs per hb ring row (16 + 4 pad)
#define NQ    4               // ring quantities: x, y, xx+yy, xy
#define NPIX  (NIMG * IMG_H * IMG_W)

// Gaussian(sigma=1.5, 11 taps), normalized fp32 — matches reference window.
__device__ __forceinline__ float gw(int k) {
    constexpr float G[KW] = {
        0.00102838f, 0.00759876f, 0.03600077f, 0.10936070f, 0.21300554f,
        0.26601173f,
        0.21300554f, 0.10936070f, 0.03600077f, 0.00759876f, 0.00102838f};
    return G[k];
}

__device__ __forceinline__ unsigned h2u(__half2 v) {
    union { __half2 h; unsigned u; } c; c.h = v; return c.u;
}
__device__ __forceinline__ __half2 u2h(unsigned v) {
    union { unsigned u; __half2 h; } c; c.u = v; return c.h;
}
// halfs (w[idx], w[idx+1]) from packed word array; odd idx = v_alignbit.
__device__ __forceinline__ __half2 hsel(const unsigned* hw, int idx) {
    unsigned r;
    if (idx & 1) r = (hw[idx >> 1] >> 16) | (hw[(idx >> 1) + 1] << 16);
    else         r = hw[idx >> 1];
    return u2h(r);
}

// R21 per-wave kernel, repackaged into 128-thread (2-wave) blocks:
// R16/R21 capacity cuts nulled because measured occupancy (~11 waves/CU)
// was bounded by WORK GRANULARITY (2048 blocks = 8/CU in ~2 dispatch
// rounds, ramp+tail dominate), not LDS/VGPR. 4096 blocks x 10,240 B LDS
// -> 15 resident blocks/CU = 30 waves (94% of the 8-wave/SIMD VGPR cap),
// identical per-wave instruction stream.
__global__ __launch_bounds__(128, 8) void ssim_strip_kernel(
        const float* __restrict__ img1, const float* __restrict__ img2,
        float* __restrict__ partial, int atomic_mode) {
    __shared__ __align__(16) __half hb[2][NQ][RING][WPAD];   // 10,240 B
    __shared__ float wsum[2];

    const int t = threadIdx.x;
    const int wid = t >> 6;
    const int lane = t & 63;
    const int tile_y = blockIdx.y * STRIP;
    const int wx = blockIdx.x * TX + wid * WTX;   // wave's first output col
    const size_t img_off = (size_t)blockIdx.z * (IMG_H * IMG_W);
    const float* p1 = img1 + img_off;
    const float* p2 = img2 + img_off;

    const bool x_ok = (wx >= 8) && (wx + 24 <= IMG_W);

    // Phase A step a: h-blur halo rows h = 16a + (lane>>2) into the wave's
    // ring slot h&31, col group g4 = lane&3 (4 cols each).
    auto phaseA = [&](int a) {
        const int lr = lane >> 2;
        const int g4 = lane & 3;
        const int h = ASTEP * a + lr;
        if (h >= HBROWS) return;
        const int rr = h & (RING - 1);
        const int gr = tile_y + h - RAD;
        const int gc0 = wx + g4 * 4 - 8;
        const bool row_ok = (tile_y + ASTEP * a - RAD >= 0) &&
                            (tile_y + ASTEP * a + ASTEP - 1 - RAD < IMG_H);
        unsigned hwx[10], hwy[10];
        if (x_ok && row_ok) {
            const size_t base = (size_t)gr * IMG_W + gc0;
#pragma unroll
            for (int w = 0; w < 5; ++w) {
                const float4 xa = *reinterpret_cast<const float4*>(p1 + base + 4 * w);
                const float4 ya = *reinterpret_cast<const float4*>(p2 + base + 4 * w);
                hwx[2 * w]     = h2u(__floats2half2_rn(xa.x, xa.y));
                hwx[2 * w + 1] = h2u(__floats2half2_rn(xa.z, xa.w));
                hwy[2 * w]     = h2u(__floats2half2_rn(ya.x, ya.y));
                hwy[2 * w + 1] = h2u(__floats2half2_rn(ya.z, ya.w));
            }
        } else {
            const bool rowok = ((unsigned)gr < (unsigned)IMG_H);
            const float* row1 = p1 + (size_t)gr * IMG_W;
            const float* row2 = p2 + (size_t)gr * IMG_W;
#pragma unroll
            for (int w = 0; w < 5; ++w) {
                const int gc = gc0 + 4 * w;
                float4 xa = make_float4(0.f, 0.f, 0.f, 0.f);
                float4 ya = make_float4(0.f, 0.f, 0.f, 0.f);
                if (rowok) {
                    if (gc >= 0 && gc <= IMG_W - 4) {
                        xa = *reinterpret_cast<const float4*>(row1 + gc);
                        ya = *reinterpret_cast<const float4*>(row2 + gc);
                    } else if (gc > -4 && gc < IMG_W) {
                        float* ex = &xa.x;
                        float* ey = &ya.x;
#pragma unroll
                        for (int j = 0; j < 4; ++j) {
                            int g = gc + j;
                            if ((unsigned)g < (unsigned)IMG_W) {
                                ex[j] = row1[g];
                                ey[j] = row2[g];
                            }
                        }
                    }
                }
                hwx[2 * w]     = h2u(__floats2half2_rn(xa.x, xa.y));
                hwx[2 * w + 1] = h2u(__floats2half2_rn(xa.z, xa.w));
                hwy[2 * w]     = h2u(__floats2half2_rn(ya.x, ya.y));
                hwy[2 * w + 1] = h2u(__floats2half2_rn(ya.z, ya.w));
            }
        }
        __half2 A0[2], A1[2], A2[2], A3[2];
#pragma unroll
        for (int p = 0; p < 2; ++p)
            A0[p] = A1[p] = A2[p] = A3[p] = u2h(0u);
#pragma unroll
        for (int k = 0; k < KW; ++k) {
            const __half2 g2 = __float2half2_rn(gw(k));
#pragma unroll
            for (int p = 0; p < 2; ++p) {
                const int idx = 2 * p + 3 + k;
                const __half2 X = hsel(hwx, idx);
                const __half2 Y = hsel(hwy, idx);
                A0[p] = __hfma2(g2, X, A0[p]);
                A1[p] = __hfma2(g2, Y, A1[p]);
                const __half2 gx = __hmul2(g2, X);
                const __half2 gy = __hmul2(g2, Y);
                A2[p] = __hfma2(gx, X, A2[p]);
                A2[p] = __hfma2(gy, Y, A2[p]);
                A3[p] = __hfma2(gx, Y, A3[p]);
            }
        }
        *reinterpret_cast<uint2*>(&hb[wid][0][rr][g4 * 4]) = make_uint2(h2u(A0[0]), h2u(A0[1]));
        *reinterpret_cast<uint2*>(&hb[wid][1][rr][g4 * 4]) = make_uint2(h2u(A1[0]), h2u(A1[1]));
        *reinterpret_cast<uint2*>(&hb[wid][2][rr][g4 * 4]) = make_uint2(h2u(A2[0]), h2u(A2[1]));
        *reinterpret_cast<uint2*>(&hb[wid][3][rr][g4 * 4]) = make_uint2(h2u(A3[0]), h2u(A3[1]));
    };

    float lsum = 0.f;

    // Phase B step s: v-blur + SSIM for output rows 16s..16s+15.
    // lane: 2 cols (slot = lane&7 -> word) x 2 rows (r2 = (lane>>3)*2).
    auto phaseB = [&](int s) {
        __half2 gh2[KW];
#pragma unroll
        for (int k = 0; k < KW; ++k) gh2[k] = __float2half2_rn(gw(k));

        const int rbase = (BSTEP * s) & (RING - 1);   // 0,16 alternating
        const int slot = lane & 7;                    // word index (2 cols)
        const int r2 = (lane >> 3) * 2;               // 0,2,...,14
        __half2 acc[NQ][2];
#pragma unroll
        for (int q = 0; q < NQ; ++q)
#pragma unroll
            for (int j = 0; j < 2; ++j)
                acc[q][j] = u2h(0u);

#pragma unroll
        for (int q = 0; q < NQ; ++q) {
#pragma unroll
            for (int k = 0; k < KW + 1; ++k) {   // 12 rows: r2+k, k=0..11
                const int r = (rbase + r2 + k) & (RING - 1);
                const __half2 hv = u2h(
                    *reinterpret_cast<const unsigned*>(&hb[wid][q][r][slot * 2]));
#pragma unroll
                for (int j = 0; j < 2; ++j) {
                    const int kk = k - j;
                    if (kk >= 0 && kk < KW)
                        acc[q][j] = __hfma2(gh2[kk], hv, acc[q][j]);
                }
            }
        }

        const float C1 = 0.0001f;
        const float C2 = 0.0009f;
#pragma unroll
        for (int j = 0; j < 2; ++j) {
            float2 m1p = __half22float2(acc[0][j]);
            float2 m2p = __half22float2(acc[1][j]);
            float2 Sp  = __half22float2(acc[2][j]);   // blur(xx+yy)
            float2 Pp  = __half22float2(acc[3][j]);   // blur(xy)
#pragma unroll
            for (int e = 0; e < 2; ++e) {
                float m1 = e ? m1p.y : m1p.x;
                float m2 = e ? m2p.y : m2p.x;
                float S  = e ? Sp.y  : Sp.x;
                float P  = e ? Pp.y  : Pp.x;
                float m1s = m1 * m1;
                float m2s = m2 * m2;
                float m12 = m1 * m2;
                float sigsum = S - m1s - m2s;
                float sig12  = P - m12;
                float num = (2.f * m12 + C1) * (2.f * sig12 + C2);
                float den = (m1s + m2s + C1) * (sigsum + C2);
                lsum = fmaf(num, __builtin_amdgcn_rcpf(den), lsum);
            }
        }
    };

    // Barrier-free per-wave schedule: A0 A1 | B0 A2 | B1 A3 | ... | B7.
    phaseA(0);
    phaseA(1);
#pragma unroll 1
    for (int s = 0; s < 8; ++s) {
        phaseB(s);
        if (s + 2 <= 8) phaseA(s + 2);
    }

    // ---- block reduction (single barrier of the kernel) ----
#pragma unroll
    for (int off = 32; off > 0; off >>= 1)
        lsum += __shfl_down(lsum, off, 64);
    if (lane == 0) wsum[wid] = lsum;
    __syncthreads();
    if (t == 0) {
        float s = wsum[0] + wsum[1];
        if (atomic_mode) {
            atomicAdd(partial, s);
        } else {
            int bid = (blockIdx.z * gridDim.y + blockIdx.y) * gridDim.x + blockIdx.x;
            partial[bid] = s;
        }
    }
}

__global__ __launch_bounds__(256) void ssim_reduce_kernel(
        const float* __restrict__ partial, int n, float* __restrict__ out) {
    float s = 0.f;
    for (int i = threadIdx.x; i < n; i += 256) s += partial[i];
#pragma unroll
    for (int off = 32; off > 0; off >>= 1)
        s += __shfl_down(s, off, 64);
    __shared__ float ws[4];
    if ((threadIdx.x & 63) == 0) ws[threadIdx.x >> 6] = s;
    __syncthreads();
    if (threadIdx.x == 0) {
        float tot = ws[0] + ws[1] + ws[2] + ws[3];
        out[0] = 1.f - tot / (float)NPIX;
    }
}

extern "C" void kernel_launch(void* const* d_in, const int* in_sizes, int n_in,
                              void* d_out, int out_size, void* d_ws, size_t ws_size,
                              hipStream_t stream) {
    const float* img1 = (const float*)d_in[0];
    const float* img2 = (const float*)d_in[1];
    float* out = (float*)d_out;
    float* partial = (float*)d_ws;

    dim3 grid(IMG_W / TX, IMG_H / STRIP, NIMG);   // 32 x 8 x 16 = 4096 blocks
    const int nblocks = (IMG_W / TX) * (IMG_H / STRIP) * NIMG;
    const size_t needed = (size_t)nblocks * sizeof(float);

    if (ws_size >= needed) {
        ssim_strip_kernel<<<grid, 128, 0, stream>>>(img1, img2, partial, 0);
        ssim_reduce_kernel<<<1, 256, 0, stream>>>(partial, nblocks, out);
    } else {
        hipMemsetAsync(d_ws, 0, sizeof(float), stream);
        ssim_strip_kernel<<<grid, 128, 0, stream>>>(img1, img2, partial, 1);
        ssim_reduce_kernel<<<1, 256, 0, stream>>>(partial, 1, out);
    }
}

// Round 23
// 88.964 us; speedup vs baseline: 3.3145x; 3.3145x over previous
//
#include <hip/hip_runtime.h>
#include <hip/hip_fp16.h>

#define IMG_H 1024
#define IMG_W 1024
#define NIMG  16
#define RAD   5
#define KW    11
#define TX    32              // block tile width (cols); 16 per wave, 2 waves
#define WTX   16              // cols per wave
#define STRIP 128             // tile height (rows per block)
#define ASTEP 16              // h-blur rows per A step
#define BSTEP 16              // output rows per B step
#define HBROWS (STRIP + 2*RAD)   // 138 h-blurred rows per strip
#define RING  32              // ring rows per wave (pow2: slot = h & 31)
#define WPAD  20              // halfs per hb ring row (16 + 4 pad)
#define NQ    4               // ring quantities: x, y, xx+yy, xy
#define NPIX  (NIMG * IMG_H * IMG_W)

// Gaussian(sigma=1.5, 11 taps), normalized fp32 — matches reference window.
__device__ __forceinline__ float gw(int k) {
    constexpr float G[KW] = {
        0.00102838f, 0.00759876f, 0.03600077f, 0.10936070f, 0.21300554f,
        0.26601173f,
        0.21300554f, 0.10936070f, 0.03600077f, 0.00759876f, 0.00102838f};
    return G[k];
}

__device__ __forceinline__ unsigned h2u(__half2 v) {
    union { __half2 h; unsigned u; } c; c.h = v; return c.u;
}
__device__ __forceinline__ __half2 u2h(unsigned v) {
    union { unsigned u; __half2 h; } c; c.u = v; return c.h;
}
// halfs (w[idx], w[idx+1]) from packed word array; odd idx = v_alignbit.
__device__ __forceinline__ __half2 hsel(const unsigned* hw, int idx) {
    unsigned r;
    if (idx & 1) r = (hw[idx >> 1] >> 16) | (hw[(idx >> 1) + 1] << 16);
    else         r = hw[idx >> 1];
    return u2h(r);
}

// R22 retry with the spill fixed: launch_bounds(128, 8) set a 32-VGPR
// target -> 620 MB scratch (R22: 294us despite 58% occupancy). The bound
// is the ALLOCATOR TARGET on this compiler; any target <64 is fatal for
// this body (R7/R8/R22). (128, 4) = 128-reg budget, where this exact
// kernel lands ~60 VGPR clean (R13/R17/R21); HW can still co-schedule
// 8 waves/SIMD at <=64 actual. 4096 blocks x 10,240 B -> 15 blocks/CU.
__global__ __launch_bounds__(128, 4) void ssim_strip_kernel(
        const float* __restrict__ img1, const float* __restrict__ img2,
        float* __restrict__ partial, int atomic_mode) {
    __shared__ __align__(16) __half hb[2][NQ][RING][WPAD];   // 10,240 B
    __shared__ float wsum[2];

    const int t = threadIdx.x;
    const int wid = t >> 6;
    const int lane = t & 63;
    const int tile_y = blockIdx.y * STRIP;
    const int wx = blockIdx.x * TX + wid * WTX;   // wave's first output col
    const size_t img_off = (size_t)blockIdx.z * (IMG_H * IMG_W);
    const float* p1 = img1 + img_off;
    const float* p2 = img2 + img_off;

    const bool x_ok = (wx >= 8) && (wx + 24 <= IMG_W);

    // Phase A step a: h-blur halo rows h = 16a + (lane>>2) into the wave's
    // ring slot h&31, col group g4 = lane&3 (4 cols each).
    auto phaseA = [&](int a) {
        const int lr = lane >> 2;
        const int g4 = lane & 3;
        const int h = ASTEP * a + lr;
        if (h >= HBROWS) return;
        const int rr = h & (RING - 1);
        const int gr = tile_y + h - RAD;
        const int gc0 = wx + g4 * 4 - 8;
        const bool row_ok = (tile_y + ASTEP * a - RAD >= 0) &&
                            (tile_y + ASTEP * a + ASTEP - 1 - RAD < IMG_H);
        unsigned hwx[10], hwy[10];
        if (x_ok && row_ok) {
            const size_t base = (size_t)gr * IMG_W + gc0;
#pragma unroll
            for (int w = 0; w < 5; ++w) {
                const float4 xa = *reinterpret_cast<const float4*>(p1 + base + 4 * w);
                const float4 ya = *reinterpret_cast<const float4*>(p2 + base + 4 * w);
                hwx[2 * w]     = h2u(__floats2half2_rn(xa.x, xa.y));
                hwx[2 * w + 1] = h2u(__floats2half2_rn(xa.z, xa.w));
                hwy[2 * w]     = h2u(__floats2half2_rn(ya.x, ya.y));
                hwy[2 * w + 1] = h2u(__floats2half2_rn(ya.z, ya.w));
            }
        } else {
            const bool rowok = ((unsigned)gr < (unsigned)IMG_H);
            const float* row1 = p1 + (size_t)gr * IMG_W;
            const float* row2 = p2 + (size_t)gr * IMG_W;
#pragma unroll
            for (int w = 0; w < 5; ++w) {
                const int gc = gc0 + 4 * w;
                float4 xa = make_float4(0.f, 0.f, 0.f, 0.f);
                float4 ya = make_float4(0.f, 0.f, 0.f, 0.f);
                if (rowok) {
                    if (gc >= 0 && gc <= IMG_W - 4) {
                        xa = *reinterpret_cast<const float4*>(row1 + gc);
                        ya = *reinterpret_cast<const float4*>(row2 + gc);
                    } else if (gc > -4 && gc < IMG_W) {
                        float* ex = &xa.x;
                        float* ey = &ya.x;
#pragma unroll
                        for (int j = 0; j < 4; ++j) {
                            int g = gc + j;
                            if ((unsigned)g < (unsigned)IMG_W) {
                                ex[j] = row1[g];
                                ey[j] = row2[g];
                            }
                        }
                    }
                }
                hwx[2 * w]     = h2u(__floats2half2_rn(xa.x, xa.y));
                hwx[2 * w + 1] = h2u(__floats2half2_rn(xa.z, xa.w));
                hwy[2 * w]     = h2u(__floats2half2_rn(ya.x, ya.y));
                hwy[2 * w + 1] = h2u(__floats2half2_rn(ya.z, ya.w));
            }
        }
        __half2 A0[2], A1[2], A2[2], A3[2];
#pragma unroll
        for (int p = 0; p < 2; ++p)
            A0[p] = A1[p] = A2[p] = A3[p] = u2h(0u);
#pragma unroll
        for (int k = 0; k < KW; ++k) {
            const __half2 g2 = __float2half2_rn(gw(k));
#pragma unroll
            for (int p = 0; p < 2; ++p) {
                const int idx = 2 * p + 3 + k;
                const __half2 X = hsel(hwx, idx);
                const __half2 Y = hsel(hwy, idx);
                A0[p] = __hfma2(g2, X, A0[p]);
                A1[p] = __hfma2(g2, Y, A1[p]);
                const __half2 gx = __hmul2(g2, X);
                const __half2 gy = __hmul2(g2, Y);
                A2[p] = __hfma2(gx, X, A2[p]);
                A2[p] = __hfma2(gy, Y, A2[p]);
                A3[p] = __hfma2(gx, Y, A3[p]);
            }
        }
        *reinterpret_cast<uint2*>(&hb[wid][0][rr][g4 * 4]) = make_uint2(h2u(A0[0]), h2u(A0[1]));
        *reinterpret_cast<uint2*>(&hb[wid][1][rr][g4 * 4]) = make_uint2(h2u(A1[0]), h2u(A1[1]));
        *reinterpret_cast<uint2*>(&hb[wid][2][rr][g4 * 4]) = make_uint2(h2u(A2[0]), h2u(A2[1]));
        *reinterpret_cast<uint2*>(&hb[wid][3][rr][g4 * 4]) = make_uint2(h2u(A3[0]), h2u(A3[1]));
    };

    float lsum = 0.f;

    // Phase B step s: v-blur + SSIM for output rows 16s..16s+15.
    // lane: 2 cols (slot = lane&7 -> word) x 2 rows (r2 = (lane>>3)*2).
    auto phaseB = [&](int s) {
        __half2 gh2[KW];
#pragma unroll
        for (int k = 0; k < KW; ++k) gh2[k] = __float2half2_rn(gw(k));

        const int rbase = (BSTEP * s) & (RING - 1);   // 0,16 alternating
        const int slot = lane & 7;                    // word index (2 cols)
        const int r2 = (lane >> 3) * 2;               // 0,2,...,14
        __half2 acc[NQ][2];
#pragma unroll
        for (int q = 0; q < NQ; ++q)
#pragma unroll
            for (int j = 0; j < 2; ++j)
                acc[q][j] = u2h(0u);

#pragma unroll
        for (int q = 0; q < NQ; ++q) {
#pragma unroll
            for (int k = 0; k < KW + 1; ++k) {   // 12 rows: r2+k, k=0..11
                const int r = (rbase + r2 + k) & (RING - 1);
                const __half2 hv = u2h(
                    *reinterpret_cast<const unsigned*>(&hb[wid][q][r][slot * 2]));
#pragma unroll
                for (int j = 0; j < 2; ++j) {
                    const int kk = k - j;
                    if (kk >= 0 && kk < KW)
                        acc[q][j] = __hfma2(gh2[kk], hv, acc[q][j]);
                }
            }
        }

        const float C1 = 0.0001f;
        const float C2 = 0.0009f;
#pragma unroll
        for (int j = 0; j < 2; ++j) {
            float2 m1p = __half22float2(acc[0][j]);
            float2 m2p = __half22float2(acc[1][j]);
            float2 Sp  = __half22float2(acc[2][j]);   // blur(xx+yy)
            float2 Pp  = __half22float2(acc[3][j]);   // blur(xy)
#pragma unroll
            for (int e = 0; e < 2; ++e) {
                float m1 = e ? m1p.y : m1p.x;
                float m2 = e ? m2p.y : m2p.x;
                float S  = e ? Sp.y  : Sp.x;
                float P  = e ? Pp.y  : Pp.x;
                float m1s = m1 * m1;
                float m2s = m2 * m2;
                float m12 = m1 * m2;
                float sigsum = S - m1s - m2s;
                float sig12  = P - m12;
                float num = (2.f * m12 + C1) * (2.f * sig12 + C2);
                float den = (m1s + m2s + C1) * (sigsum + C2);
                lsum = fmaf(num, __builtin_amdgcn_rcpf(den), lsum);
            }
        }
    };

    // Barrier-free per-wave schedule: A0 A1 | B0 A2 | B1 A3 | ... | B7.
    phaseA(0);
    phaseA(1);
#pragma unroll 1
    for (int s = 0; s < 8; ++s) {
        phaseB(s);
        if (s + 2 <= 8) phaseA(s + 2);
    }

    // ---- block reduction (single barrier of the kernel) ----
#pragma unroll
    for (int off = 32; off > 0; off >>= 1)
        lsum += __shfl_down(lsum, off, 64);
    if (lane == 0) wsum[wid] = lsum;
    __syncthreads();
    if (t == 0) {
        float s = wsum[0] + wsum[1];
        if (atomic_mode) {
            atomicAdd(partial, s);
        } else {
            int bid = (blockIdx.z * gridDim.y + blockIdx.y) * gridDim.x + blockIdx.x;
            partial[bid] = s;
        }
    }
}

__global__ __launch_bounds__(256) void ssim_reduce_kernel(
        const float* __restrict__ partial, int n, float* __restrict__ out) {
    float s = 0.f;
    for (int i = threadIdx.x; i < n; i += 256) s += partial[i];
#pragma unroll
    for (int off = 32; off > 0; off >>= 1)
        s += __shfl_down(s, off, 64);
    __shared__ float ws[4];
    if ((threadIdx.x & 63) == 0) ws[threadIdx.x >> 6] = s;
    __syncthreads();
    if (threadIdx.x == 0) {
        float tot = ws[0] + ws[1] + ws[2] + ws[3];
        out[0] = 1.f - tot / (float)NPIX;
    }
}

extern "C" void kernel_launch(void* const* d_in, const int* in_sizes, int n_in,
                              void* d_out, int out_size, void* d_ws, size_t ws_size,
                              hipStream_t stream) {
    const float* img1 = (const float*)d_in[0];
    const float* img2 = (const float*)d_in[1];
    float* out = (float*)d_out;
    float* partial = (float*)d_ws;

    dim3 grid(IMG_W / TX, IMG_H / STRIP, NIMG);   // 32 x 8 x 16 = 4096 blocks
    const int nblocks = (IMG_W / TX) * (IMG_H / STRIP) * NIMG;
    const size_t needed = (size_t)nblocks * sizeof(float);

    if (ws_size >= needed) {
        ssim_strip_kernel<<<grid, 128, 0, stream>>>(img1, img2, partial, 0);
        ssim_reduce_kernel<<<1, 256, 0, stream>>>(partial, nblocks, out);
    } else {
        hipMemsetAsync(d_ws, 0, sizeof(float), stream);
        ssim_strip_kernel<<<grid, 128, 0, stream>>>(img1, img2, partial, 1);
        ssim_reduce_kernel<<<1, 256, 0, stream>>>(partial, 1, out);
    }
}

// Round 24
// 73.353 us; speedup vs baseline: 4.0199x; 1.2128x over previous
//
#include <hip/hip_runtime.h>
#include <hip/hip_fp16.h>

#define IMG_H 1024
#define IMG_W 1024
#define NIMG  16
#define RAD   5
#define KW    11
#define TX    64              // block tile width (cols); 16 per wave, 4 waves
#define WTX   16              // cols per wave
#define STRIP 64              // tile height (rows per block) — granularity probe
#define ASTEP 16              // h-blur rows per A step
#define BSTEP 16              // output rows per B step
#define HBROWS (STRIP + 2*RAD)   // 74 h-blurred rows per strip
#define RING  32              // ring rows per wave (pow2: slot = h & 31)
#define WPAD  20              // halfs per hb ring row (16 + 4 pad)
#define NQ    4               // ring quantities: x, y, xx+yy, xy
#define NPIX  (NIMG * IMG_H * IMG_W)

// Gaussian(sigma=1.5, 11 taps), normalized fp32 — matches reference window.
__device__ __forceinline__ float gw(int k) {
    constexpr float G[KW] = {
        0.00102838f, 0.00759876f, 0.03600077f, 0.10936070f, 0.21300554f,
        0.26601173f,
        0.21300554f, 0.10936070f, 0.03600077f, 0.00759876f, 0.00102838f};
    return G[k];
}

__device__ __forceinline__ unsigned h2u(__half2 v) {
    union { __half2 h; unsigned u; } c; c.h = v; return c.u;
}
__device__ __forceinline__ __half2 u2h(unsigned v) {
    union { unsigned u; __half2 h; } c; c.u = v; return c.h;
}
// halfs (w[idx], w[idx+1]) from packed word array; odd idx = v_alignbit.
__device__ __forceinline__ __half2 hsel(const unsigned* hw, int idx) {
    unsigned r;
    if (idx & 1) r = (hw[idx >> 1] >> 16) | (hw[(idx >> 1) + 1] << 16);
    else         r = hw[idx >> 1];
    return u2h(r);
}

// R21 body, STRIP 128->64 (granularity probe, un-confounded):
// R23 showed TX=32 inflates FETCH (1.5x x-span, lost L2 halo dedup);
// shrinking STRIP instead keeps TX=64 4-wave blocks (x-traffic identical,
// y-neighbors 16 apart in linear id = same XCD -> L2 dedups halo rows)
// while doubling schedulable units: 4096 blocks, half per-block duration,
// ramp/tail imbalance halves. LDS unchanged (ring is per-wave).
// Ring safety (HBROWS=74): A0 A1 | B0 A2 | B1 A3 | B2 A4 | B3 —
// B0 h0-25 (A0,A1 wrote h0-31); A2 h32-47=slots 0-15 overwrites h0-15
// last read by B0; B1 h16-41 (A2 done); A3 h48-63=slots 16-31 overwrites
// h16-31 last read by B1; B2 h32-57; A4 h64-73=slots 0-9 overwrites
// h32-41 last read by B2; B3 h48-73. All enforced by wave program order.
__global__ __launch_bounds__(256, 4) void ssim_strip_kernel(
        const float* __restrict__ img1, const float* __restrict__ img2,
        float* __restrict__ partial, int atomic_mode) {
    __shared__ __align__(16) __half hb[4][NQ][RING][WPAD];   // 20,480 B
    __shared__ float wsum[4];

    const int t = threadIdx.x;
    const int wid = t >> 6;
    const int lane = t & 63;
    const int tile_y = blockIdx.y * STRIP;
    const int wx = blockIdx.x * TX + wid * WTX;   // wave's first output col
    const size_t img_off = (size_t)blockIdx.z * (IMG_H * IMG_W);
    const float* p1 = img1 + img_off;
    const float* p2 = img2 + img_off;

    const bool x_ok = (wx >= 8) && (wx + 24 <= IMG_W);

    // Phase A step a: h-blur halo rows h = 16a + (lane>>2) into the wave's
    // ring slot h&31, col group g4 = lane&3 (4 cols each).
    auto phaseA = [&](int a) {
        const int lr = lane >> 2;
        const int g4 = lane & 3;
        const int h = ASTEP * a + lr;
        if (h >= HBROWS) return;
        const int rr = h & (RING - 1);
        const int gr = tile_y + h - RAD;
        const int gc0 = wx + g4 * 4 - 8;
        const bool row_ok = (tile_y + ASTEP * a - RAD >= 0) &&
                            (tile_y + ASTEP * a + ASTEP - 1 - RAD < IMG_H);
        unsigned hwx[10], hwy[10];
        if (x_ok && row_ok) {
            const size_t base = (size_t)gr * IMG_W + gc0;
#pragma unroll
            for (int w = 0; w < 5; ++w) {
                const float4 xa = *reinterpret_cast<const float4*>(p1 + base + 4 * w);
                const float4 ya = *reinterpret_cast<const float4*>(p2 + base + 4 * w);
                hwx[2 * w]     = h2u(__floats2half2_rn(xa.x, xa.y));
                hwx[2 * w + 1] = h2u(__floats2half2_rn(xa.z, xa.w));
                hwy[2 * w]     = h2u(__floats2half2_rn(ya.x, ya.y));
                hwy[2 * w + 1] = h2u(__floats2half2_rn(ya.z, ya.w));
            }
        } else {
            const bool rowok = ((unsigned)gr < (unsigned)IMG_H);
            const float* row1 = p1 + (size_t)gr * IMG_W;
            const float* row2 = p2 + (size_t)gr * IMG_W;
#pragma unroll
            for (int w = 0; w < 5; ++w) {
                const int gc = gc0 + 4 * w;
                float4 xa = make_float4(0.f, 0.f, 0.f, 0.f);
                float4 ya = make_float4(0.f, 0.f, 0.f, 0.f);
                if (rowok) {
                    if (gc >= 0 && gc <= IMG_W - 4) {
                        xa = *reinterpret_cast<const float4*>(row1 + gc);
                        ya = *reinterpret_cast<const float4*>(row2 + gc);
                    } else if (gc > -4 && gc < IMG_W) {
                        float* ex = &xa.x;
                        float* ey = &ya.x;
#pragma unroll
                        for (int j = 0; j < 4; ++j) {
                            int g = gc + j;
                            if ((unsigned)g < (unsigned)IMG_W) {
                                ex[j] = row1[g];
                                ey[j] = row2[g];
                            }
                        }
                    }
                }
                hwx[2 * w]     = h2u(__floats2half2_rn(xa.x, xa.y));
                hwx[2 * w + 1] = h2u(__floats2half2_rn(xa.z, xa.w));
                hwy[2 * w]     = h2u(__floats2half2_rn(ya.x, ya.y));
                hwy[2 * w + 1] = h2u(__floats2half2_rn(ya.z, ya.w));
            }
        }
        __half2 A0[2], A1[2], A2[2], A3[2];
#pragma unroll
        for (int p = 0; p < 2; ++p)
            A0[p] = A1[p] = A2[p] = A3[p] = u2h(0u);
#pragma unroll
        for (int k = 0; k < KW; ++k) {
            const __half2 g2 = __float2half2_rn(gw(k));
#pragma unroll
            for (int p = 0; p < 2; ++p) {
                const int idx = 2 * p + 3 + k;
                const __half2 X = hsel(hwx, idx);
                const __half2 Y = hsel(hwy, idx);
                A0[p] = __hfma2(g2, X, A0[p]);
                A1[p] = __hfma2(g2, Y, A1[p]);
                const __half2 gx = __hmul2(g2, X);
                const __half2 gy = __hmul2(g2, Y);
                A2[p] = __hfma2(gx, X, A2[p]);
                A2[p] = __hfma2(gy, Y, A2[p]);
                A3[p] = __hfma2(gx, Y, A3[p]);
            }
        }
        *reinterpret_cast<uint2*>(&hb[wid][0][rr][g4 * 4]) = make_uint2(h2u(A0[0]), h2u(A0[1]));
        *reinterpret_cast<uint2*>(&hb[wid][1][rr][g4 * 4]) = make_uint2(h2u(A1[0]), h2u(A1[1]));
        *reinterpret_cast<uint2*>(&hb[wid][2][rr][g4 * 4]) = make_uint2(h2u(A2[0]), h2u(A2[1]));
        *reinterpret_cast<uint2*>(&hb[wid][3][rr][g4 * 4]) = make_uint2(h2u(A3[0]), h2u(A3[1]));
    };

    float lsum = 0.f;

    // Phase B step s: v-blur + SSIM for output rows 16s..16s+15.
    // lane: 2 cols (slot = lane&7 -> word) x 2 rows (r2 = (lane>>3)*2).
    auto phaseB = [&](int s) {
        __half2 gh2[KW];
#pragma unroll
        for (int k = 0; k < KW; ++k) gh2[k] = __float2half2_rn(gw(k));

        const int rbase = (BSTEP * s) & (RING - 1);   // 0,16 alternating
        const int slot = lane & 7;                    // word index (2 cols)
        const int r2 = (lane >> 3) * 2;               // 0,2,...,14
        __half2 acc[NQ][2];
#pragma unroll
        for (int q = 0; q < NQ; ++q)
#pragma unroll
            for (int j = 0; j < 2; ++j)
                acc[q][j] = u2h(0u);

#pragma unroll
        for (int q = 0; q < NQ; ++q) {
#pragma unroll
            for (int k = 0; k < KW + 1; ++k) {   // 12 rows: r2+k, k=0..11
                const int r = (rbase + r2 + k) & (RING - 1);
                const __half2 hv = u2h(
                    *reinterpret_cast<const unsigned*>(&hb[wid][q][r][slot * 2]));
#pragma unroll
                for (int j = 0; j < 2; ++j) {
                    const int kk = k - j;
                    if (kk >= 0 && kk < KW)
                        acc[q][j] = __hfma2(gh2[kk], hv, acc[q][j]);
                }
            }
        }

        const float C1 = 0.0001f;
        const float C2 = 0.0009f;
#pragma unroll
        for (int j = 0; j < 2; ++j) {
            float2 m1p = __half22float2(acc[0][j]);
            float2 m2p = __half22float2(acc[1][j]);
            float2 Sp  = __half22float2(acc[2][j]);   // blur(xx+yy)
            float2 Pp  = __half22float2(acc[3][j]);   // blur(xy)
#pragma unroll
            for (int e = 0; e < 2; ++e) {
                float m1 = e ? m1p.y : m1p.x;
                float m2 = e ? m2p.y : m2p.x;
                float S  = e ? Sp.y  : Sp.x;
                float P  = e ? Pp.y  : Pp.x;
                float m1s = m1 * m1;
                float m2s = m2 * m2;
                float m12 = m1 * m2;
                float sigsum = S - m1s - m2s;
                float sig12  = P - m12;
                float num = (2.f * m12 + C1) * (2.f * sig12 + C2);
                float den = (m1s + m2s + C1) * (sigsum + C2);
                lsum = fmaf(num, __builtin_amdgcn_rcpf(den), lsum);
            }
        }
    };

    // Barrier-free per-wave schedule: A0 A1 | B0 A2 | B1 A3 | B2 A4 | B3.
    phaseA(0);
    phaseA(1);
#pragma unroll 1
    for (int s = 0; s < 4; ++s) {
        phaseB(s);
        if (s + 2 <= 4) phaseA(s + 2);
    }

    // ---- block reduction (single barrier of the kernel) ----
#pragma unroll
    for (int off = 32; off > 0; off >>= 1)
        lsum += __shfl_down(lsum, off, 64);
    if (lane == 0) wsum[wid] = lsum;
    __syncthreads();
    if (t == 0) {
        float s = wsum[0] + wsum[1] + wsum[2] + wsum[3];
        if (atomic_mode) {
            atomicAdd(partial, s);
        } else {
            int bid = (blockIdx.z * gridDim.y + blockIdx.y) * gridDim.x + blockIdx.x;
            partial[bid] = s;
        }
    }
}

__global__ __launch_bounds__(256) void ssim_reduce_kernel(
        const float* __restrict__ partial, int n, float* __restrict__ out) {
    float s = 0.f;
    for (int i = threadIdx.x; i < n; i += 256) s += partial[i];
#pragma unroll
    for (int off = 32; off > 0; off >>= 1)
        s += __shfl_down(s, off, 64);
    __shared__ float ws[4];
    if ((threadIdx.x & 63) == 0) ws[threadIdx.x >> 6] = s;
    __syncthreads();
    if (threadIdx.x == 0) {
        float tot = ws[0] + ws[1] + ws[2] + ws[3];
        out[0] = 1.f - tot / (float)NPIX;
    }
}

extern "C" void kernel_launch(void* const* d_in, const int* in_sizes, int n_in,
                              void* d_out, int out_size, void* d_ws, size_t ws_size,
                              hipStream_t stream) {
    const float* img1 = (const float*)d_in[0];
    const float* img2 = (const float*)d_in[1];
    float* out = (float*)d_out;
    float* partial = (float*)d_ws;

    dim3 grid(IMG_W / TX, IMG_H / STRIP, NIMG);   // 16 x 16 x 16 = 4096 blocks
    const int nblocks = (IMG_W / TX) * (IMG_H / STRIP) * NIMG;
    const size_t needed = (size_t)nblocks * sizeof(float);

    if (ws_size >= needed) {
        ssim_strip_kernel<<<grid, 256, 0, stream>>>(img1, img2, partial, 0);
        ssim_reduce_kernel<<<1, 256, 0, stream>>>(partial, nblocks, out);
    } else {
        hipMemsetAsync(d_ws, 0, sizeof(float), stream);
        ssim_strip_kernel<<<grid, 256, 0, stream>>>(img1, img2, partial, 1);
        ssim_reduce_kernel<<<1, 256, 0, stream>>>(partial, 1, out);
    }
}

// Round 25
// 67.682 us; speedup vs baseline: 4.3568x; 1.0838x over previous
//
#include <hip/hip_runtime.h>
#include <hip/hip_fp16.h>

#define IMG_H 1024
#define IMG_W 1024
#define NIMG  16
#define RAD   5
#define KW    11
#define TX    64              // block tile width (cols); 16 per wave
#define WTX   16              // cols per wave
#define STRIP 128             // tile height (rows per block)
#define ASTEP 16              // h-blur rows per A step
#define BSTEP 32              // output rows per B step
#define HBROWS (STRIP + 2*RAD)   // 138 h-blurred rows per strip
#define RING  48              // ring rows per wave
#define WPAD  20              // halfs per hb ring row (16 + 4 pad)
#define NQ    4               // ring quantities: x, y, xx+yy, xy
#define NPIX  (NIMG * IMG_H * IMG_W)

// Gaussian(sigma=1.5, 11 taps), normalized fp32 — matches reference window.
__device__ __forceinline__ float gw(int k) {
    constexpr float G[KW] = {
        0.00102838f, 0.00759876f, 0.03600077f, 0.10936070f, 0.21300554f,
        0.26601173f,
        0.21300554f, 0.10936070f, 0.03600077f, 0.00759876f, 0.00102838f};
    return G[k];
}

__device__ __forceinline__ unsigned h2u(__half2 v) {
    union { __half2 h; unsigned u; } c; c.h = v; return c.u;
}
__device__ __forceinline__ __half2 u2h(unsigned v) {
    union { unsigned u; __half2 h; } c; c.u = v; return c.h;
}
// halfs (w[idx], w[idx+1]) from packed word array; odd idx = v_alignbit.
__device__ __forceinline__ __half2 hsel(const unsigned* hw, int idx) {
    unsigned r;
    if (idx & 1) r = (hw[idx >> 1] >> 16) | (hw[(idx >> 1) + 1] << 16);
    else         r = hw[idx >> 1];
    return u2h(r);
}

// FINAL (R17 restoration, best measured: 67.7 us):
// - wave-private rings, ZERO main-loop barriers (R17's -12%: block-wide
//   lockstep was the floor; per-wave program order + compiler lgkmcnt
//   provides all needed ordering)
// - fp16-packed h-blur windows in registers (R13: kills SROA scratch spill)
// - 4-quantity algebra: x, y, xx+yy, xy (R16: sigma1_sq+sigma2_sq =
//   blur(xx+yy) - mu1^2 - mu2^2)
// Plateau ledger (R18-R24): bank conflicts are a layout-invariant b64
// service floor (R19/R20); LDS capacity, work granularity, L1-dedup
// staging, deep prefetch all null or regress. Latency-bound at ~54% VALU.
__global__ __launch_bounds__(256, 8) void ssim_strip_kernel(
        const float* __restrict__ img1, const float* __restrict__ img2,
        float* __restrict__ partial, int atomic_mode) {
    __shared__ __align__(16) __half hb[4][NQ][RING][WPAD];   // 30,720 B
    __shared__ float wsum[4];

    const int t = threadIdx.x;
    const int wid = t >> 6;
    const int lane = t & 63;
    const int tile_y = blockIdx.y * STRIP;
    const int wx = blockIdx.x * TX + wid * WTX;   // wave's first output col
    const size_t img_off = (size_t)blockIdx.z * (IMG_H * IMG_W);
    const float* p1 = img1 + img_off;
    const float* p2 = img2 + img_off;

    const bool x_ok = (wx >= 8) && (wx + 24 <= IMG_W);

    // Phase A step a: h-blur halo rows h = 16a + (lane>>2) into the wave's
    // ring slot h%48, col group g4 = lane&3 (4 cols each).
    auto phaseA = [&](int a) {
        const int lr = lane >> 2;
        const int g4 = lane & 3;
        const int h = ASTEP * a + lr;
        if (h >= HBROWS) return;
        int rr = h;
        if (rr >= 96) rr -= 96;
        else if (rr >= RING) rr -= RING;
        const int gr = tile_y + h - RAD;
        const int gc0 = wx + g4 * 4 - 8;
        const bool row_ok = (tile_y + ASTEP * a - RAD >= 0) &&
                            (tile_y + ASTEP * a + ASTEP - 1 - RAD < IMG_H);
        unsigned hwx[10], hwy[10];
        if (x_ok && row_ok) {
            const size_t base = (size_t)gr * IMG_W + gc0;
#pragma unroll
            for (int w = 0; w < 5; ++w) {
                const float4 xa = *reinterpret_cast<const float4*>(p1 + base + 4 * w);
                const float4 ya = *reinterpret_cast<const float4*>(p2 + base + 4 * w);
                hwx[2 * w]     = h2u(__floats2half2_rn(xa.x, xa.y));
                hwx[2 * w + 1] = h2u(__floats2half2_rn(xa.z, xa.w));
                hwy[2 * w]     = h2u(__floats2half2_rn(ya.x, ya.y));
                hwy[2 * w + 1] = h2u(__floats2half2_rn(ya.z, ya.w));
            }
        } else {
            const bool rowok = ((unsigned)gr < (unsigned)IMG_H);
            const float* row1 = p1 + (size_t)gr * IMG_W;
            const float* row2 = p2 + (size_t)gr * IMG_W;
#pragma unroll
            for (int w = 0; w < 5; ++w) {
                const int gc = gc0 + 4 * w;
                float4 xa = make_float4(0.f, 0.f, 0.f, 0.f);
                float4 ya = make_float4(0.f, 0.f, 0.f, 0.f);
                if (rowok) {
                    if (gc >= 0 && gc <= IMG_W - 4) {
                        xa = *reinterpret_cast<const float4*>(row1 + gc);
                        ya = *reinterpret_cast<const float4*>(row2 + gc);
                    } else if (gc > -4 && gc < IMG_W) {
                        float* ex = &xa.x;
                        float* ey = &ya.x;
#pragma unroll
                        for (int j = 0; j < 4; ++j) {
                            int g = gc + j;
                            if ((unsigned)g < (unsigned)IMG_W) {
                                ex[j] = row1[g];
                                ey[j] = row2[g];
                            }
                        }
                    }
                }
                hwx[2 * w]     = h2u(__floats2half2_rn(xa.x, xa.y));
                hwx[2 * w + 1] = h2u(__floats2half2_rn(xa.z, xa.w));
                hwy[2 * w]     = h2u(__floats2half2_rn(ya.x, ya.y));
                hwy[2 * w + 1] = h2u(__floats2half2_rn(ya.z, ya.w));
            }
        }
        __half2 A0[2], A1[2], A2[2], A3[2];
#pragma unroll
        for (int p = 0; p < 2; ++p)
            A0[p] = A1[p] = A2[p] = A3[p] = u2h(0u);
#pragma unroll
        for (int k = 0; k < KW; ++k) {
            const __half2 g2 = __float2half2_rn(gw(k));
#pragma unroll
            for (int p = 0; p < 2; ++p) {
                const int idx = 2 * p + 3 + k;
                const __half2 X = hsel(hwx, idx);
                const __half2 Y = hsel(hwy, idx);
                A0[p] = __hfma2(g2, X, A0[p]);
                A1[p] = __hfma2(g2, Y, A1[p]);
                const __half2 gx = __hmul2(g2, X);
                const __half2 gy = __hmul2(g2, Y);
                A2[p] = __hfma2(gx, X, A2[p]);
                A2[p] = __hfma2(gy, Y, A2[p]);
                A3[p] = __hfma2(gx, Y, A3[p]);
            }
        }
        *reinterpret_cast<uint2*>(&hb[wid][0][rr][g4 * 4]) = make_uint2(h2u(A0[0]), h2u(A0[1]));
        *reinterpret_cast<uint2*>(&hb[wid][1][rr][g4 * 4]) = make_uint2(h2u(A1[0]), h2u(A1[1]));
        *reinterpret_cast<uint2*>(&hb[wid][2][rr][g4 * 4]) = make_uint2(h2u(A2[0]), h2u(A2[1]));
        *reinterpret_cast<uint2*>(&hb[wid][3][rr][g4 * 4]) = make_uint2(h2u(A3[0]), h2u(A3[1]));
    };

    float lsum = 0.f;

    // Phase B step s: v-blur + SSIM for output rows 32s..32s+31.
    // lane: 4 cols (slot = lane&3) x 2 rows (r2 = (lane>>2)*2).
    auto phaseB = [&](int s) {
        __half2 gh2[KW];
#pragma unroll
        for (int k = 0; k < KW; ++k) gh2[k] = __float2half2_rn(gw(k));

        const int rbase = (BSTEP * s) % RING;   // 0,32,16,0
        const int slot = lane & 3;
        const int r2 = (lane >> 2) * 2;
        __half2 acc[NQ][2][2];
#pragma unroll
        for (int q = 0; q < NQ; ++q)
#pragma unroll
            for (int rl = 0; rl < 2; ++rl)
#pragma unroll
                for (int cp = 0; cp < 2; ++cp)
                    acc[q][rl][cp] = u2h(0u);

#pragma unroll
        for (int q = 0; q < NQ; ++q) {
#pragma unroll
            for (int k = 0; k < KW + 1; ++k) {
                int r = rbase + r2 + k;
                if (r >= RING) r -= RING;
                const uint2 rv =
                    *reinterpret_cast<const uint2*>(&hb[wid][q][r][slot * 4]);
                __half2 h0 = u2h(rv.x);
                __half2 h1 = u2h(rv.y);
                if (k < KW) {
                    acc[q][0][0] = __hfma2(gh2[k], h0, acc[q][0][0]);
                    acc[q][0][1] = __hfma2(gh2[k], h1, acc[q][0][1]);
                }
                if (k > 0) {
                    acc[q][1][0] = __hfma2(gh2[k - 1], h0, acc[q][1][0]);
                    acc[q][1][1] = __hfma2(gh2[k - 1], h1, acc[q][1][1]);
                }
            }
        }

        const float C1 = 0.0001f;
        const float C2 = 0.0009f;
#pragma unroll
        for (int rl = 0; rl < 2; ++rl) {
#pragma unroll
            for (int cp = 0; cp < 2; ++cp) {
                float2 m1p = __half22float2(acc[0][rl][cp]);
                float2 m2p = __half22float2(acc[1][rl][cp]);
                float2 Sp  = __half22float2(acc[2][rl][cp]);   // blur(xx+yy)
                float2 Pp  = __half22float2(acc[3][rl][cp]);   // blur(xy)
#pragma unroll
                for (int e = 0; e < 2; ++e) {
                    float m1 = e ? m1p.y : m1p.x;
                    float m2 = e ? m2p.y : m2p.x;
                    float S  = e ? Sp.y  : Sp.x;
                    float P  = e ? Pp.y  : Pp.x;
                    float m1s = m1 * m1;
                    float m2s = m2 * m2;
                    float m12 = m1 * m2;
                    float sigsum = S - m1s - m2s;
                    float sig12  = P - m12;
                    float num = (2.f * m12 + C1) * (2.f * sig12 + C2);
                    float den = (m1s + m2s + C1) * (sigsum + C2);
                    lsum = fmaf(num, __builtin_amdgcn_rcpf(den), lsum);
                }
            }
        }
    };

    // Barrier-free per-wave schedule (ring safety: RING=48/ASTEP=16/BSTEP=32
    // stepping verified in R9/R16; enforced by wave program order).
#pragma unroll 1
    for (int a = 0; a < 9; ++a) {
        phaseA(a);
        if (a >= 2 && ((a & 1) == 0)) {
            phaseB((a - 2) >> 1);
        }
    }

    // ---- block reduction (single barrier of the kernel) ----
#pragma unroll
    for (int off = 32; off > 0; off >>= 1)
        lsum += __shfl_down(lsum, off, 64);
    if (lane == 0) wsum[wid] = lsum;
    __syncthreads();
    if (t == 0) {
        float s = wsum[0] + wsum[1] + wsum[2] + wsum[3];
        if (atomic_mode) {
            atomicAdd(partial, s);
        } else {
            int bid = (blockIdx.z * gridDim.y + blockIdx.y) * gridDim.x + blockIdx.x;
            partial[bid] = s;
        }
    }
}

__global__ __launch_bounds__(256) void ssim_reduce_kernel(
        const float* __restrict__ partial, int n, float* __restrict__ out) {
    float s = 0.f;
    for (int i = threadIdx.x; i < n; i += 256) s += partial[i];
#pragma unroll
    for (int off = 32; off > 0; off >>= 1)
        s += __shfl_down(s, off, 64);
    __shared__ float ws[4];
    if ((threadIdx.x & 63) == 0) ws[threadIdx.x >> 6] = s;
    __syncthreads();
    if (threadIdx.x == 0) {
        float tot = ws[0] + ws[1] + ws[2] + ws[3];
        out[0] = 1.f - tot / (float)NPIX;
    }
}

extern "C" void kernel_launch(void* const* d_in, const int* in_sizes, int n_in,
                              void* d_out, int out_size, void* d_ws, size_t ws_size,
                              hipStream_t stream) {
    const float* img1 = (const float*)d_in[0];
    const float* img2 = (const float*)d_in[1];
    float* out = (float*)d_out;
    float* partial = (float*)d_ws;

    dim3 grid(IMG_W / TX, IMG_H / STRIP, NIMG);   // 16 x 8 x 16 = 2048 blocks
    const int nblocks = (IMG_W / TX) * (IMG_H / STRIP) * NIMG;
    const size_t needed = (size_t)nblocks * sizeof(float);

    if (ws_size >= needed) {
        ssim_strip_kernel<<<grid, 256, 0, stream>>>(img1, img2, partial, 0);
        ssim_reduce_kernel<<<1, 256, 0, stream>>>(partial, nblocks, out);
    } else {
        hipMemsetAsync(d_ws, 0, sizeof(float), stream);
        ssim_strip_kernel<<<grid, 256, 0, stream>>>(img1, img2, partial, 1);
        ssim_reduce_kernel<<<1, 256, 0, stream>>>(partial, 1, out);
    }
}